// Round 2
// baseline (111.682 us; speedup 1.0000x reference)
//
#include <hip/hip_runtime.h>
#include <hip/hip_bf16.h>

// Shapes: B=2, C=256, H=W=24 (HW=576), G=16, Cg=16, GRID=25, AC=6400, Mg=400
// Inputs fp32, output fp32.
// ws layout: h1b (bf16 ushort)[4,718,592] | pooled f32[204,800] | (aff slot unused)
// Harness floor: d_ws fill ~41 us (measured R1: 268MB @ 6.5TB/s, roofline) +
//   ~28 us aux dispatches. Controllable: k12 + gaps + k4 (~42 us @ R1).
// LESSON (R9): per-lane arrays indexed ONLY by compile-time constants.
// LESSON (R11/R12): no work duplication in k12; >=4 MFMA per phase-2 strip.
// LESSON (R14): non-pow2 LDS pitches; no per-element rsqrt.
// LESSON (R16/R17): barriers and LDS size are NOT the stall; occupancy fixed
//   at 4 waves/SIMD (512 thr). 8 waves/SIMD needs <=64 VGPR -> impossible with
//   w2r/dreg/af2 live state; occupancy lever is exhausted.
// R19 (this round): (a) fuse k3 into k4 (aff computed redundantly per block
//   from L2-hot pooled; kills one dispatch + gap); (b) float4 x-staging in k12
//   (18 scalar dword loads -> 5 float4 loads per thread).

typedef __attribute__((ext_vector_type(8))) short short8;
typedef __attribute__((ext_vector_type(4))) float f32x4;

static __device__ __forceinline__ unsigned short f2bf(float x) {
    unsigned u = __float_as_uint(x);
    unsigned r = (u + 0x7fffu + ((u >> 16) & 1u)) >> 16;   // RNE
    return (unsigned short)r;
}

// LDS overlay (40,160 B; 2 blocks/CU = 80.3 KB of 160 KB):
//  phase A: xs [row27][col26][ci p24] @0 (33,696) | wA [kk5][co16][k p40] @33,696 (6,400)
//  phase B: hsb [s576][j p20] @0 (23,040) | wlb [m400][j16] @23,040 (12,800)
//           bias2 @35,840 (1,600) | pacc @37,440 (1,600) | zpad @39,040 (16)
//  bias1 [16] @40,096 (64)
#define WA_OFF   33696
#define WLB_OFF  23040
#define B2_OFF   35840
#define PACC_OFF 37440
#define ZP_OFF   39040
#define BB1_OFF  40096
#define SMEM_BYTES 40160

// Grid 512 x 512 threads (8 waves): tile T = tt*8 + w, tt=0..3 all waves,
// tt=4 only waves 0-3 (wave-uniform guard, compile-time array indices).
__global__ __launch_bounds__(512, 4) void k12_fused(
    const float* __restrict__ xin,
    const float* __restrict__ W1,
    const float* __restrict__ g1, const float* __restrict__ b1,
    const float* __restrict__ m1, const float* __restrict__ v1,
    const float* __restrict__ W2,
    const float* __restrict__ g2, const float* __restrict__ b2,
    const float* __restrict__ m2, const float* __restrict__ v2,
    unsigned short* __restrict__ h1b,
    float* __restrict__ pooled)
{
    __shared__ __align__(16) char smem[SMEM_BYTES];
    short* xs    = (short*)smem;
    short* wAp   = (short*)(smem + WA_OFF);
    short* hsb   = (short*)smem;
    short* wlb   = (short*)(smem + WLB_OFF);
    float* bias2 = (float*)(smem + B2_OFF);
    float* pacc  = (float*)(smem + PACC_OFF);
    float* bias1 = (float*)(smem + BB1_OFF);

    int bid = blockIdx.x;                      // i*32 + b*16 + g
    int i = bid >> 5, b = (bid >> 4) & 1, g = bid & 15;
    int t = threadIdx.x;

    // ---- W2 preload into registers (1 m per thread; latency overlapped) ----
    float4 w2r[4];
    float  bsc;
    {
        bool act = (t < 400);
        int o = i*6400 + g*400 + (act ? t : 0);
        float s2 = g2[o] * rsqrtf(v2[o] + 1e-5f);
        bsc = b2[o] - m2[o] * s2;
        const float4* wr = (const float4*)&W2[o*16];
#pragma unroll
        for (int q = 0; q < 4; q++) {
            float4 wv = wr[q];
            wv.x *= s2; wv.y *= s2; wv.z *= s2; wv.w *= s2;
            w2r[q] = wv;
        }
    }

    // ---- staging: bias1, halo-zero xs, interior xs (float4), wA ----
    if (t < 16) {
        int c = i*256 + g*16 + t;
        float sc = g1[c] * rsqrtf(v1[c] + 1e-5f);
        bias1[t] = b1[c] - m1[c] * sc;
    }
    {
        int* xz = (int*)xs;
        for (int idx = t; idx < 1512; idx += 512) {
            int c = idx / 12, j = idx - (idx / 12) * 12;
            int row, col;
            if (c < 26)      { row = 0;  col = c; }
            else if (c < 52) { row = 25; col = c - 26; }
            else if (c < 78) { row = 26; col = c - 52; }
            else { int k = c - 78; row = 1 + (k >> 1); col = (k & 1) ? 25 : 0; }
            xz[(row*26 + col)*12 + j] = 0;
        }
    }
    {
        // 9216 floats = 2304 float4 (each float4 = 4 px, same ci, same row:
        // x%4==0 and x+3<=23 always). LDS px stride = 24 shorts.
        const float4* xb4 = (const float4*)&xin[(b*256 + g*16)*576];
        for (int idx = t; idx < 2304; idx += 512) {
            float4 v = xb4[idx];
            int f = idx * 4;
            int ci = f / 576; int s = f - ci*576;
            int y = s / 24; int x = s - y*24;
            int base = ((y+1)*26 + (x+1))*24 + ci;
            xs[base     ] = (short)f2bf(v.x);
            xs[base + 24] = (short)f2bf(v.y);
            xs[base + 48] = (short)f2bf(v.z);
            xs[base + 72] = (short)f2bf(v.w);
        }
    }
    {
        const float* wb = &W1[(i*256 + g*16)*144];    // [co][ci][9]
        for (int idx = t; idx < 2560; idx += 512) {
            int kk = idx >> 9, rem = idx & 511, co = rem >> 5, k = rem & 31;
            int tap = 2*kk + (k >> 4), ci = k & 15;
            int c = i*256 + g*16 + co;
            float sc = g1[c] * rsqrtf(v1[c] + 1e-5f);
            float val = (tap < 9) ? wb[co*144 + ci*9 + tap] * sc : 0.f;
            wAp[(kk*16 + co)*40 + k] = (short)f2bf(val);
        }
    }
    __syncthreads();                           // #1: staging complete

    int l = t & 63, w = t >> 6;                // 8 waves; tiles T = tt*8 + w
    int quad = l >> 4, rc = l & 15;
    bool five = (w < 4);                       // waves 0-3 own a 5th tile

    // ---- phase 1: D(16co x 576px) = W1'(16x144)*im2col + bias1 ----
    f32x4 dreg[5];
    {
        int ci0 = (quad & 1) * 8;
        short8 afr[5];
#pragma unroll
        for (int kk = 0; kk < 5; kk++)
            afr[kk] = *(const short8*)&wAp[(kk*16 + rc)*40 + quad*8];
        f32x4 cb1 = *(const f32x4*)&bias1[quad*4];

        const int offE[5] = {0, 48, 648, 1248, 1296};     // taps 0,2,4,6,8
        const int offO[5] = {24, 624, 672, 1272, 1872};   // taps 1,3,5,7,9(A=0)
        int off[5];
#pragma unroll
        for (int kk = 0; kk < 5; kk++) off[kk] = (quad >= 2) ? offO[kk] : offE[kk];

#pragma unroll
        for (int tt = 0; tt < 5; tt++) {
            if (tt == 4 && !five) break;       // wave-uniform
            int s = (tt*8 + w)*16 + rc;
            int y = s / 24; int x = s - y*24;
            int base = (y*26 + x)*24 + ci0;
            f32x4 acc = cb1;
#pragma unroll
            for (int kk = 0; kk < 5; kk++) {
                short8 bf = *(const short8*)&xs[base + off[kk]];
                acc = __builtin_amdgcn_mfma_f32_16x16x32_bf16(afr[kk], bf, acc, 0, 0, 0);
            }
#pragma unroll
            for (int r = 0; r < 4; r++) acc[r] = fmaxf(acc[r], 0.f);
            dreg[tt] = acc;
        }
    }
    __syncthreads();                           // #2: xs/wA reads done

    // ---- hsb (own tiles) + h1b global; wlb/bias2 from registers; pacc/zpad ----
    {
        unsigned short* hout = &h1b[((i*2 + b)*256 + g*16)*576];
#pragma unroll
        for (int tt = 0; tt < 5; tt++) {
            if (tt == 4 && !five) break;
            int s = (tt*8 + w)*16 + rc;
            f32x4 acc = dreg[tt];
            unsigned short e0 = f2bf(acc[0]), e1 = f2bf(acc[1]);
            unsigned short e2 = f2bf(acc[2]), e3 = f2bf(acc[3]);
            uint2 pk = {(unsigned)e0 | ((unsigned)e1 << 16),
                        (unsigned)e2 | ((unsigned)e3 << 16)};
            *(uint2*)&hsb[s*20 + quad*4] = pk;
            hout[(quad*4 + 0)*576 + s] = e0;
            hout[(quad*4 + 1)*576 + s] = e1;
            hout[(quad*4 + 2)*576 + s] = e2;
            hout[(quad*4 + 3)*576 + s] = e3;
        }
    }
    if (t < 400) {
        pacc[t]  = 0.f;
        bias2[t] = bsc;
#pragma unroll
        for (int q = 0; q < 4; q++) {
            float4 wv = w2r[q];
            wlb[t*16 + q*4 + 0] = (short)f2bf(wv.x);
            wlb[t*16 + q*4 + 1] = (short)f2bf(wv.y);
            wlb[t*16 + q*4 + 2] = (short)f2bf(wv.z);
            wlb[t*16 + q*4 + 3] = (short)f2bf(wv.w);
        }
    }
    if (t < 4) ((int*)(smem + ZP_OFF))[t] = 0;
    __syncthreads();                           // #3: wlb/bias2/pacc ready

    // ---- phase 2 (transposed, registered A): D2[s,m] = h(s,j)*W2'(j,m)+be[m]
    {
        int q8 = (quad & 1) * 8;               // j-offset quads 0/1; 2/3 read zpad
        short8 af2[5];
#pragma unroll
        for (int u = 0; u < 5; u++) {
            bool valid = (l < 32) && (u < 4 || five);
            int boff = valid ? ((((u*8 + w)*16 + rc)*20 + q8)*2) : ZP_OFF;
            af2[u] = *(const short8*)(smem + boff);
        }
        for (int mt = 0; mt < 25; mt++) {
            int m0 = mt*16;
            int woff = (l < 32) ? (WLB_OFF + ((m0 + rc)*16 + q8)*2) : ZP_OFF;
            short8 wf = *(const short8*)(smem + woff);
            float be = bias2[m0 + rc];
            f32x4 cb = {be, be, be, be};       // bias per column m

            f32x4 accv = {0.f, 0.f, 0.f, 0.f};
#pragma unroll
            for (int u = 0; u < 4; u++) {      // tiles all waves own
                f32x4 d = __builtin_amdgcn_mfma_f32_16x16x32_bf16(af2[u], wf, cb, 0, 0, 0);
#pragma unroll
                for (int r = 0; r < 4; r++)
                    accv[r] += fmaxf(d[r], 0.f);
            }
            if (five) {                        // 5th tile, waves 0-3 only
                f32x4 d = __builtin_amdgcn_mfma_f32_16x16x32_bf16(af2[4], wf, cb, 0, 0, 0);
#pragma unroll
                for (int r = 0; r < 4; r++)
                    accv[r] += fmaxf(d[r], 0.f);
            }
            float a = (accv[0] + accv[1]) + (accv[2] + accv[3]);
            a += __shfl_xor(a, 16);            // sum 4 quads = 16 rows per tile
            a += __shfl_xor(a, 32);
            if (l < 16)
                atomicAdd(&pacc[m0 + l], a);   // ds_add_f32, 8 waves per addr
        }
    }
    __syncthreads();                           // #4: pacc complete

    const float inv = 1.f / 676.f;             // 26x26 pool incl. 100 border px
    if (t < 400) {
        float be = bias2[t];
        pooled[(i*2+b)*6400 + g*400 + t] =
            (pacc[t] + 100.f * fmaxf(be, 0.f)) * inv;
    }
}

// k4: aff prologue (fused former k3; redundant per block, pooled is L2-hot)
//     + output contraction; quad-pixel loads (uint2 = 4 bf16 px), float4 stores.
__global__ __launch_bounds__(256) void k4_out(const unsigned short* __restrict__ h1b,
                                              const float* __restrict__ pooled,
                                              float* __restrict__ out)
{
    __shared__ float a0[16], a1[16];
    int bid = blockIdx.x;           // i*32 + q*16 + cg
    int i = bid >> 5, q = (bid >> 4) & 1, cg = bid & 15;
    int t = threadIdx.x;

    // ---- aff[(i,b),l] = (1/16) sum_m pooled[(i,b),i*400+m]*pooled[(i,b),l*400+m]
    // 32 (b,l) pairs x 8 threads; float2 strided loads; shfl-reduce j=0..7.
    {
        int p = t >> 3, j = t & 7;             // pair p = b*16 + l
        int bb = p >> 4, l = p & 15;
        const float* pb = &pooled[(i*2 + bb)*6400];
        const float2* pth = (const float2*)(pb + i*400);
        const float2* pl  = (const float2*)(pb + l*400);
        float s = 0.f;
#pragma unroll 5
        for (int f = j; f < 200; f += 8) {     // 200 float2 = 400 floats
            float2 a = pth[f], c = pl[f];
            s = fmaf(a.x, c.x, s);
            s = fmaf(a.y, c.y, s);
        }
        s += __shfl_xor(s, 1);
        s += __shfl_xor(s, 2);
        s += __shfl_xor(s, 4);
        if (j == 0) {
            float v = s * (1.f/16.f);
            if (bb == 0) a0[l] = v; else a1[l] = v;
        }
    }
    __syncthreads();

    if (t >= 144) return;
    const unsigned short* hb = &h1b[((i*2+q)*256 + cg)*576];
    int ch = i*32 + q*16 + cg;
    int s = t*4;                    // 144 quads cover 576 px
    float c00=0.f,c01=0.f,c02=0.f,c03=0.f;
    float c10=0.f,c11=0.f,c12=0.f,c13=0.f;
#pragma unroll
    for (int k = 0; k < 16; k++) {
        uint2 hv = *(const uint2*)&hb[k*9216 + s];
        float p0 = __uint_as_float(hv.x << 16);
        float p1 = __uint_as_float(hv.x & 0xffff0000u);
        float p2 = __uint_as_float(hv.y << 16);
        float p3 = __uint_as_float(hv.y & 0xffff0000u);
        float va = a0[k], vb = a1[k];
        c00 = fmaf(va, p0, c00); c01 = fmaf(va, p1, c01);
        c02 = fmaf(va, p2, c02); c03 = fmaf(va, p3, c03);
        c10 = fmaf(vb, p0, c10); c11 = fmaf(vb, p1, c11);
        c12 = fmaf(vb, p2, c12); c13 = fmaf(vb, p3, c13);
    }
    float4 o0 = {c00, c01, c02, c03};
    float4 o1 = {c10, c11, c12, c13};
    *(float4*)&out[ch*576 + s]         = o0;
    *(float4*)&out[(512 + ch)*576 + s] = o1;
}

extern "C" void kernel_launch(void* const* d_in, const int* in_sizes, int n_in,
                              void* d_out, int out_size, void* d_ws, size_t ws_size,
                              hipStream_t stream)
{
    const float* x  = (const float*)d_in[0];
    const float* W1 = (const float*)d_in[1];
    const float* g1 = (const float*)d_in[2];
    const float* b1 = (const float*)d_in[3];
    const float* m1 = (const float*)d_in[4];
    const float* v1 = (const float*)d_in[5];
    const float* W2 = (const float*)d_in[6];
    const float* g2 = (const float*)d_in[7];
    const float* b2 = (const float*)d_in[8];
    const float* m2 = (const float*)d_in[9];
    const float* v2 = (const float*)d_in[10];

    unsigned short* h1b = (unsigned short*)d_ws;          // 4,718,592 ushorts
    float* pooled = (float*)(h1b + 16*2*256*576);         // 204,800 floats

    float* out = (float*)d_out;

    hipLaunchKernelGGL(k12_fused, dim3(512), dim3(512), 0, stream,
                       x, W1, g1, b1, m1, v1, W2, g2, b2, m2, v2, h1b, pooled);
    hipLaunchKernelGGL(k4_out,    dim3(512), dim3(256), 0, stream,
                       h1b, pooled, out);
}

// Round 3
// 109.708 us; speedup vs baseline: 1.0180x; 1.0180x over previous
//
#include <hip/hip_runtime.h>
#include <hip/hip_bf16.h>

// Shapes: B=2, C=256, H=W=24 (HW=576), G=16, Cg=16, GRID=25, AC=6400, Mg=400
// ws layout: h1b (bf16 ushort)[4,718,592] | pooled f32[204,800]
// Harness floor: d_ws fill ~41-43 us (268MB @ ~6.4TB/s, roofline) + ~28 us aux.
// Controllable: k12 + k4 (~42 us). R1/R2: top-5 counters are all fills ->
//   k12 invisible to profiler window; judge by dur_us.
// LESSON (R9): per-lane arrays indexed ONLY by compile-time constants.
// LESSON (R11/R12): no work duplication in k12; >=4 MFMA per phase-2 strip.
// LESSON (R14): non-pow2 LDS pitches (xs pitch 24: 2-way max, free).
// LESSON (R16/R17): occupancy 4 waves/SIMD via 512-thr blocks.
// R19 (R2): k3 fused into k4; float4 x-staging. NEUTRAL (fill noise masked
//   ~1-2us gain) -> gaps/k3 were not material; k12 internals are the target.
// R20 (this round): phase-2 via mfma 16x16x16bf16_1k. Lane (quad,rc)'s dreg
//   IS the A-fragment (k=quad*4+e == co) -> hsb LDS round-trip DELETED
//   (23KB, 5 ds_write_b64 + 5 ds_read_b128/thread), zpad deleted, K-half
//   zero-waste deleted. wlb/bias2/pacc staged pre-bar#1 (no xs overlap now:
//   56,160B static). Barriers 4 -> 2; waves flow phase1->phase2 freely.

typedef __attribute__((ext_vector_type(8))) short short8;
typedef __attribute__((ext_vector_type(4))) short short4b;
typedef __attribute__((ext_vector_type(4))) float f32x4;

static __device__ __forceinline__ unsigned short f2bf(float x) {
    unsigned u = __float_as_uint(x);
    unsigned r = (u + 0x7fffu + ((u >> 16) & 1u)) >> 16;   // RNE
    return (unsigned short)r;
}

// LDS layout (56,160 B static; 2 blocks/CU = 112.3 KB of 160 KB):
//  xs [row27][col26][ci p24] @0 (33,696) | wA [kk5][co16][k p40] @33,696 (6,400)
//  wlb [m400][j16] @40,096 (12,800) | bias2 @52,896 (1,600)
//  pacc @54,496 (1,600) | bias1 @56,096 (64)
#define WA_OFF   33696
#define WLB_OFF  40096
#define B2_OFF   52896
#define PACC_OFF 54496
#define BB1_OFF  56096
#define SMEM_BYTES 56160

// Grid 512 x 512 threads (8 waves): tile T = tt*8 + w, tt=0..3 all waves,
// tt=4 only waves 0-3 (wave-uniform guard, compile-time array indices).
__global__ __launch_bounds__(512, 4) void k12_fused(
    const float* __restrict__ xin,
    const float* __restrict__ W1,
    const float* __restrict__ g1, const float* __restrict__ b1,
    const float* __restrict__ m1, const float* __restrict__ v1,
    const float* __restrict__ W2,
    const float* __restrict__ g2, const float* __restrict__ b2,
    const float* __restrict__ m2, const float* __restrict__ v2,
    unsigned short* __restrict__ h1b,
    float* __restrict__ pooled)
{
    __shared__ __align__(16) char smem[SMEM_BYTES];
    short* xs    = (short*)smem;
    short* wAp   = (short*)(smem + WA_OFF);
    short* wlb   = (short*)(smem + WLB_OFF);
    float* bias2 = (float*)(smem + B2_OFF);
    float* pacc  = (float*)(smem + PACC_OFF);
    float* bias1 = (float*)(smem + BB1_OFF);

    int bid = blockIdx.x;                      // i*32 + b*16 + g
    int i = bid >> 5, b = (bid >> 4) & 1, g = bid & 15;
    int t = threadIdx.x;

    // ---- W2 preload into registers (1 m per thread; latency overlapped) ----
    float4 w2r[4];
    float  bsc;
    {
        bool act = (t < 400);
        int o = i*6400 + g*400 + (act ? t : 0);
        float s2 = g2[o] * rsqrtf(v2[o] + 1e-5f);
        bsc = b2[o] - m2[o] * s2;
        const float4* wr = (const float4*)&W2[o*16];
#pragma unroll
        for (int q = 0; q < 4; q++) {
            float4 wv = wr[q];
            wv.x *= s2; wv.y *= s2; wv.z *= s2; wv.w *= s2;
            w2r[q] = wv;
        }
    }

    // ---- staging: bias1, halo-zero xs, interior xs (float4), wA ----
    if (t < 16) {
        int c = i*256 + g*16 + t;
        float sc = g1[c] * rsqrtf(v1[c] + 1e-5f);
        bias1[t] = b1[c] - m1[c] * sc;
    }
    {
        int* xz = (int*)xs;
        for (int idx = t; idx < 1512; idx += 512) {
            int c = idx / 12, j = idx - (idx / 12) * 12;
            int row, col;
            if (c < 26)      { row = 0;  col = c; }
            else if (c < 52) { row = 25; col = c - 26; }
            else if (c < 78) { row = 26; col = c - 52; }
            else { int k = c - 78; row = 1 + (k >> 1); col = (k & 1) ? 25 : 0; }
            xz[(row*26 + col)*12 + j] = 0;
        }
    }
    {
        // 9216 floats = 2304 float4 (each float4 = 4 px, same ci, same row).
        const float4* xb4 = (const float4*)&xin[(b*256 + g*16)*576];
        for (int idx = t; idx < 2304; idx += 512) {
            float4 v = xb4[idx];
            int f = idx * 4;
            int ci = f / 576; int s = f - ci*576;
            int y = s / 24; int x = s - y*24;
            int base = ((y+1)*26 + (x+1))*24 + ci;
            xs[base     ] = (short)f2bf(v.x);
            xs[base + 24] = (short)f2bf(v.y);
            xs[base + 48] = (short)f2bf(v.z);
            xs[base + 72] = (short)f2bf(v.w);
        }
    }
    {
        const float* wb = &W1[(i*256 + g*16)*144];    // [co][ci][9]
        for (int idx = t; idx < 2560; idx += 512) {
            int kk = idx >> 9, rem = idx & 511, co = rem >> 5, k = rem & 31;
            int tap = 2*kk + (k >> 4), ci = k & 15;
            int c = i*256 + g*16 + co;
            float sc = g1[c] * rsqrtf(v1[c] + 1e-5f);
            float val = (tap < 9) ? wb[co*144 + ci*9 + tap] * sc : 0.f;
            wAp[(kk*16 + co)*40 + k] = (short)f2bf(val);
        }
    }
    // ---- wlb/bias2/pacc staged pre-barrier (from w2r regs; frees w2r early)
    if (t < 400) {
        pacc[t]  = 0.f;
        bias2[t] = bsc;
        uint4 pkA, pkB;
        pkA.x = (unsigned)f2bf(w2r[0].x) | ((unsigned)f2bf(w2r[0].y) << 16);
        pkA.y = (unsigned)f2bf(w2r[0].z) | ((unsigned)f2bf(w2r[0].w) << 16);
        pkA.z = (unsigned)f2bf(w2r[1].x) | ((unsigned)f2bf(w2r[1].y) << 16);
        pkA.w = (unsigned)f2bf(w2r[1].z) | ((unsigned)f2bf(w2r[1].w) << 16);
        pkB.x = (unsigned)f2bf(w2r[2].x) | ((unsigned)f2bf(w2r[2].y) << 16);
        pkB.y = (unsigned)f2bf(w2r[2].z) | ((unsigned)f2bf(w2r[2].w) << 16);
        pkB.z = (unsigned)f2bf(w2r[3].x) | ((unsigned)f2bf(w2r[3].y) << 16);
        pkB.w = (unsigned)f2bf(w2r[3].z) | ((unsigned)f2bf(w2r[3].w) << 16);
        *(uint4*)&wlb[t*16]     = pkA;
        *(uint4*)&wlb[t*16 + 8] = pkB;
    }
    __syncthreads();                           // #1: ALL staging complete

    int l = t & 63, w = t >> 6;                // 8 waves; tiles T = tt*8 + w
    int quad = l >> 4, rc = l & 15;
    bool five = (w < 4);                       // waves 0-3 own a 5th tile

    // ---- phase 1: D(16co x 576px) = W1'(16x144)*im2col + bias1 ----
    f32x4 dreg[5];
    {
        int ci0 = (quad & 1) * 8;
        short8 afr[5];
#pragma unroll
        for (int kk = 0; kk < 5; kk++)
            afr[kk] = *(const short8*)&wAp[(kk*16 + rc)*40 + quad*8];
        f32x4 cb1 = *(const f32x4*)&bias1[quad*4];

        const int offE[5] = {0, 48, 648, 1248, 1296};     // taps 0,2,4,6,8
        const int offO[5] = {24, 624, 672, 1272, 1872};   // taps 1,3,5,7,9(=0)
        int off[5];
#pragma unroll
        for (int kk = 0; kk < 5; kk++) off[kk] = (quad >= 2) ? offO[kk] : offE[kk];

#pragma unroll
        for (int tt = 0; tt < 5; tt++) {
            if (tt == 4 && !five) break;       // wave-uniform
            int s = (tt*8 + w)*16 + rc;
            int y = s / 24; int x = s - y*24;
            int base = (y*26 + x)*24 + ci0;
            f32x4 acc = cb1;
#pragma unroll
            for (int kk = 0; kk < 5; kk++) {
                short8 bf = *(const short8*)&xs[base + off[kk]];
                acc = __builtin_amdgcn_mfma_f32_16x16x32_bf16(afr[kk], bf, acc, 0, 0, 0);
            }
#pragma unroll
            for (int r = 0; r < 4; r++) acc[r] = fmaxf(acc[r], 0.f);
            dreg[tt] = acc;
        }
    }
    // NO barrier: phase 2's A-fragments are this lane's own registers.

    // ---- epilogue: pack pa (A-frags for phase 2) + h1b global stores ----
    short4b pa[5];
    {
        unsigned short* hout = &h1b[((i*2 + b)*256 + g*16)*576];
#pragma unroll
        for (int tt = 0; tt < 5; tt++) {
            if (tt == 4 && !five) break;
            int s = (tt*8 + w)*16 + rc;
            f32x4 acc = dreg[tt];
            unsigned short e0 = f2bf(acc[0]), e1 = f2bf(acc[1]);
            unsigned short e2 = f2bf(acc[2]), e3 = f2bf(acc[3]);
            short4b pv;
            pv[0] = (short)e0; pv[1] = (short)e1;
            pv[2] = (short)e2; pv[3] = (short)e3;
            pa[tt] = pv;
            hout[(quad*4 + 0)*576 + s] = e0;
            hout[(quad*4 + 1)*576 + s] = e1;
            hout[(quad*4 + 2)*576 + s] = e2;
            hout[(quad*4 + 3)*576 + s] = e3;
        }
    }

    // ---- phase 2: K=16 MFMA, A from registers (pa), B from wlb ----
    // D2[s-local, m] = sum_j h[s,j] * W2'[j,m] + be[m]; relu; pool-accumulate.
    {
        for (int mt = 0; mt < 25; mt++) {
            int m0 = mt*16;
            short4b wf = *(const short4b*)&wlb[(m0 + rc)*16 + quad*4];
            float be = bias2[m0 + rc];
            f32x4 cb = {be, be, be, be};       // bias per column m

            f32x4 accv = {0.f, 0.f, 0.f, 0.f};
#pragma unroll
            for (int u = 0; u < 4; u++) {      // tiles all waves own
                f32x4 d = __builtin_amdgcn_mfma_f32_16x16x16bf16_1k(pa[u], wf, cb, 0, 0, 0);
#pragma unroll
                for (int r = 0; r < 4; r++)
                    accv[r] += fmaxf(d[r], 0.f);
            }
            if (five) {                        // 5th tile, waves 0-3 only
                f32x4 d = __builtin_amdgcn_mfma_f32_16x16x16bf16_1k(pa[4], wf, cb, 0, 0, 0);
#pragma unroll
                for (int r = 0; r < 4; r++)
                    accv[r] += fmaxf(d[r], 0.f);
            }
            float a = (accv[0] + accv[1]) + (accv[2] + accv[3]);
            a += __shfl_xor(a, 16);            // sum 4 quads = 16 rows per tile
            a += __shfl_xor(a, 32);
            if (l < 16)
                atomicAdd(&pacc[m0 + l], a);   // ds_add_f32, 8 waves per addr
        }
    }
    __syncthreads();                           // #2: pacc complete

    const float inv = 1.f / 676.f;             // 26x26 pool incl. 100 border px
    if (t < 400) {
        float be = bias2[t];
        pooled[(i*2+b)*6400 + g*400 + t] =
            (pacc[t] + 100.f * fmaxf(be, 0.f)) * inv;
    }
}

// k4: aff prologue (fused former k3; redundant per block, pooled is L2-hot)
//     + output contraction; quad-pixel loads (uint2 = 4 bf16 px), float4 stores.
__global__ __launch_bounds__(256) void k4_out(const unsigned short* __restrict__ h1b,
                                              const float* __restrict__ pooled,
                                              float* __restrict__ out)
{
    __shared__ float a0[16], a1[16];
    int bid = blockIdx.x;           // i*32 + q*16 + cg
    int i = bid >> 5, q = (bid >> 4) & 1, cg = bid & 15;
    int t = threadIdx.x;

    // ---- aff[(i,b),l] = (1/16) sum_m pooled[(i,b),i*400+m]*pooled[(i,b),l*400+m]
    {
        int p = t >> 3, j = t & 7;             // pair p = b*16 + l
        int bb = p >> 4, l = p & 15;
        const float* pb = &pooled[(i*2 + bb)*6400];
        const float2* pth = (const float2*)(pb + i*400);
        const float2* pl  = (const float2*)(pb + l*400);
        float s = 0.f;
#pragma unroll 5
        for (int f = j; f < 200; f += 8) {     // 200 float2 = 400 floats
            float2 a = pth[f], c = pl[f];
            s = fmaf(a.x, c.x, s);
            s = fmaf(a.y, c.y, s);
        }
        s += __shfl_xor(s, 1);
        s += __shfl_xor(s, 2);
        s += __shfl_xor(s, 4);
        if (j == 0) {
            float v = s * (1.f/16.f);
            if (bb == 0) a0[l] = v; else a1[l] = v;
        }
    }
    __syncthreads();

    if (t >= 144) return;
    const unsigned short* hb = &h1b[((i*2+q)*256 + cg)*576];
    int ch = i*32 + q*16 + cg;
    int s = t*4;                    // 144 quads cover 576 px
    float c00=0.f,c01=0.f,c02=0.f,c03=0.f;
    float c10=0.f,c11=0.f,c12=0.f,c13=0.f;
#pragma unroll
    for (int k = 0; k < 16; k++) {
        uint2 hv = *(const uint2*)&hb[k*9216 + s];
        float p0 = __uint_as_float(hv.x << 16);
        float p1 = __uint_as_float(hv.x & 0xffff0000u);
        float p2 = __uint_as_float(hv.y << 16);
        float p3 = __uint_as_float(hv.y & 0xffff0000u);
        float va = a0[k], vb = a1[k];
        c00 = fmaf(va, p0, c00); c01 = fmaf(va, p1, c01);
        c02 = fmaf(va, p2, c02); c03 = fmaf(va, p3, c03);
        c10 = fmaf(vb, p0, c10); c11 = fmaf(vb, p1, c11);
        c12 = fmaf(vb, p2, c12); c13 = fmaf(vb, p3, c13);
    }
    float4 o0 = {c00, c01, c02, c03};
    float4 o1 = {c10, c11, c12, c13};
    *(float4*)&out[ch*576 + s]         = o0;
    *(float4*)&out[(512 + ch)*576 + s] = o1;
}

extern "C" void kernel_launch(void* const* d_in, const int* in_sizes, int n_in,
                              void* d_out, int out_size, void* d_ws, size_t ws_size,
                              hipStream_t stream)
{
    const float* x  = (const float*)d_in[0];
    const float* W1 = (const float*)d_in[1];
    const float* g1 = (const float*)d_in[2];
    const float* b1 = (const float*)d_in[3];
    const float* m1 = (const float*)d_in[4];
    const float* v1 = (const float*)d_in[5];
    const float* W2 = (const float*)d_in[6];
    const float* g2 = (const float*)d_in[7];
    const float* b2 = (const float*)d_in[8];
    const float* m2 = (const float*)d_in[9];
    const float* v2 = (const float*)d_in[10];

    unsigned short* h1b = (unsigned short*)d_ws;          // 4,718,592 ushorts
    float* pooled = (float*)(h1b + 16*2*256*576);         // 204,800 floats

    float* out = (float*)d_out;

    hipLaunchKernelGGL(k12_fused, dim3(512), dim3(512), 0, stream,
                       x, W1, g1, b1, m1, v1, W2, g2, b2, m2, v2, h1b, pooled);
    hipLaunchKernelGGL(k4_out,    dim3(512), dim3(256), 0, stream,
                       h1b, pooled, out);
}